// Round 11
// baseline (1910.118 us; speedup 1.0000x reference)
//
#include <hip/hip_runtime.h>

// Viterbi / CRF decode: B=32, S=512, T=128.
// R11: single-block-per-batch (NO cross-CU exchange; fabric RT floor ~2-3K
// cyc/step measured across R4/R7/R9/R10 is avoided entirely) + R10's
// column-in-wave reduce (no LDS-partial phase; R2's 3-phase reduce was its
// ~3K cyc of fat). 1024 threads: thread = (col j = tid>>3, row-block
// ih = tid&7). Per step: 16-row serial chain in exact ref fp order
// ((fs[i]+t1[j])+t0[i,j], strict > = first-max), then 3 shfl_xor u64-key
// merges across the column's 8 lanes (tie byte 255-row: unsigned max ==
// exact value max + smallest-i tie-break). ih==0 lane writes fs + bp byte
// straight to LDS. ONE lgkm-only barrier per step.
// t0/t1 prefetched 2 steps deep into EXPLICIT NAMED scalar registers via
// macros (R10's lambda/array version got sunk by the compiler: VGPR=36).
// bp kept in LDS (64 KB) -> fused serial backtrack, single dispatch.

constexpr int S = 512;
constexpr int T = 128;

using u64 = unsigned long long;
using u32 = unsigned int;

__device__ __forceinline__ void bar_lds() {
    asm volatile("s_waitcnt lgkmcnt(0)" ::: "memory");
    __builtin_amdgcn_s_barrier();
}
__device__ __forceinline__ u32 flipf(u32 u)   { return u ^ (0x80000000u | (u32)((int)u >> 31)); }
__device__ __forceinline__ u32 unflipf(u32 y) { return y ^ (0x80000000u | ~(u32)((int)y >> 31)); }

__global__ __launch_bounds__(1024, 1)
void viterbi_one(const float* __restrict__ c0, const float* __restrict__ c1,
                 const int* __restrict__ sofp, const int* __restrict__ eofp,
                 int* __restrict__ out)
{
    __shared__ float fs[2][T];           // parity-double-buffered forward scores
    __shared__ unsigned char bp[S][T];   // backpointers, 64 KB

    const int b   = blockIdx.x;
    const int tid = (int)threadIdx.x;
    const int j   = tid >> 3;            // column 0..127 (8 lanes per column,
    const int ih  = tid & 7;             //  all within ONE wave: lane=8*jl+ih)
    const int r0  = ih * 16;             // this thread's 16 rows

    const float* c0b = c0 + (size_t)b * (S + 1) * T * T;
    const float* c1b = c1 + (size_t)b * (S + 1) * T;

    // fs0[j] = c0[b,0,sof,j] * c1[b,0,j]  (multiply at step 0, per reference)
    if (tid < T) fs[0][tid] = c0b[(size_t)sofp[0] * T + tid] * c1b[tid];

    // ---- 2-step-deep register prefetch: named scalars, loads can't sink ----
    const float* pA = c0b + (size_t)T * T + (size_t)r0 * T + j;   // step 1
    const float* pB = pA + T * T;                                  // step 2
    float tA = c1b[(size_t)1 * T + j];
    float tB = c1b[(size_t)2 * T + j];

#define LOAD16(P, ptr)                                                        \
    P##0  = (ptr)[0 * T];  P##1  = (ptr)[1 * T];  P##2  = (ptr)[2 * T];       \
    P##3  = (ptr)[3 * T];  P##4  = (ptr)[4 * T];  P##5  = (ptr)[5 * T];       \
    P##6  = (ptr)[6 * T];  P##7  = (ptr)[7 * T];  P##8  = (ptr)[8 * T];       \
    P##9  = (ptr)[9 * T];  P##10 = (ptr)[10 * T]; P##11 = (ptr)[11 * T];      \
    P##12 = (ptr)[12 * T]; P##13 = (ptr)[13 * T]; P##14 = (ptr)[14 * T];      \
    P##15 = (ptr)[15 * T];

    float A0, A1, A2, A3, A4, A5, A6, A7, A8, A9, A10, A11, A12, A13, A14, A15;
    float B0, B1, B2, B3, B4, B5, B6, B7, B8, B9, B10, B11, B12, B13, B14, B15;
    LOAD16(A, pA)
    LOAD16(B, pB)

    bar_lds();   // fs[0] visible

    // One step: chain over 16 rows (exact ref fp order; strict > keeps the
    // smallest row on ties), cross-lane u64-key merge, ih==0 writes fs + bp.
#define STEP(SS, P, tc)                                                       \
    {                                                                         \
        const int par = (SS) & 1;                                             \
        const float* fsr = &fs[par ^ 1][r0];                                  \
        float4 f0 = *(const float4*)(fsr);                                    \
        float4 f1 = *(const float4*)(fsr + 4);                                \
        float4 f2 = *(const float4*)(fsr + 8);                                \
        float4 f3 = *(const float4*)(fsr + 12);                               \
        float bv, v; int br;                                                  \
        bv = (f0.x + tc) + P##0;  br = 0;                                     \
        v = (f0.y + tc) + P##1;  if (v > bv) { bv = v; br = 1;  }             \
        v = (f0.z + tc) + P##2;  if (v > bv) { bv = v; br = 2;  }             \
        v = (f0.w + tc) + P##3;  if (v > bv) { bv = v; br = 3;  }             \
        v = (f1.x + tc) + P##4;  if (v > bv) { bv = v; br = 4;  }             \
        v = (f1.y + tc) + P##5;  if (v > bv) { bv = v; br = 5;  }             \
        v = (f1.z + tc) + P##6;  if (v > bv) { bv = v; br = 6;  }             \
        v = (f1.w + tc) + P##7;  if (v > bv) { bv = v; br = 7;  }             \
        v = (f2.x + tc) + P##8;  if (v > bv) { bv = v; br = 8;  }             \
        v = (f2.y + tc) + P##9;  if (v > bv) { bv = v; br = 9;  }             \
        v = (f2.z + tc) + P##10; if (v > bv) { bv = v; br = 10; }             \
        v = (f2.w + tc) + P##11; if (v > bv) { bv = v; br = 11; }             \
        v = (f3.x + tc) + P##12; if (v > bv) { bv = v; br = 12; }             \
        v = (f3.y + tc) + P##13; if (v > bv) { bv = v; br = 13; }             \
        v = (f3.z + tc) + P##14; if (v > bv) { bv = v; br = 14; }             \
        v = (f3.w + tc) + P##15; if (v > bv) { bv = v; br = 15; }             \
        u64 key = ((u64)flipf(__float_as_uint(bv)) << 32)                     \
                | (u32)(255 - (r0 + br));                                     \
        { u64 p = __shfl_xor(key, 1, 64); if (p > key) key = p; }             \
        { u64 p = __shfl_xor(key, 2, 64); if (p > key) key = p; }             \
        { u64 p = __shfl_xor(key, 4, 64); if (p > key) key = p; }             \
        if (ih == 0) {                                                        \
            fs[par][j] = __uint_as_float(unflipf((u32)(key >> 32)));          \
            bp[(SS) - 1][j] = (unsigned char)(255 - (int)(key & 0xFFu));      \
        }                                                                     \
    }

    for (int s = 1; s <= S; s += 2) {
        STEP(s, A, tA)
        if (s + 2 <= S) {               // refill A for step s+2
            pA += 2 * T * T;
            LOAD16(A, pA)
            tA = c1b[(size_t)(s + 2) * T + j];
        }
        bar_lds();

        STEP(s + 1, B, tB)
        if (s + 3 <= S) {               // refill B for step s+3
            pB += 2 * T * T;
            LOAD16(B, pB)
            tB = c1b[(size_t)(s + 3) * T + j];
        }
        bar_lds();
    }

#undef STEP
#undef LOAD16

    // Backtrack (serial pointer chase, all in LDS):
    // ptr = bp[S-1][eof]; for idx = S-1..0: ptr = bp[idx][ptr]; out[b,idx]=ptr.
    if (tid == 0) {
        const int eof = eofp[0];
        int ptr = bp[S - 1][eof];
        for (int idx = S - 1; idx >= 0; --idx) {
            ptr = bp[idx][ptr];
            out[(size_t)b * S + idx] = ptr;
        }
    }
}

extern "C" void kernel_launch(void* const* d_in, const int* in_sizes, int n_in,
                              void* d_out, int out_size, void* d_ws, size_t ws_size,
                              hipStream_t stream)
{
    const float* c0  = (const float*)d_in[0];
    const float* c1  = (const float*)d_in[1];
    const int*   sof = (const int*)d_in[2];
    const int*   eof = (const int*)d_in[3];
    int*         out = (int*)d_out;

    const int B = in_sizes[1] / ((S + 1) * T);   // 32
    viterbi_one<<<dim3(B), dim3(1024), 0, stream>>>(c0, c1, sof, eof, out);
}